// Round 1
// baseline (597.589 us; speedup 1.0000x reference)
//
#include <hip/hip_runtime.h>
#include <hip/hip_bf16.h>
#include <stdint.h>

// Problem constants
#define NB 4
#define NT 2048
#define NC 1024
#define NH 16
#define NHD 64
#define NM (NB*NT)   // 8192 rows

typedef __attribute__((ext_vector_type(8))) __bf16 bf16x8;
typedef __attribute__((ext_vector_type(4))) float floatx4;
typedef __attribute__((ext_vector_type(4))) unsigned int uintx4;

__device__ __forceinline__ unsigned short f2bf(float f) {
    union { float f; unsigned int u; } v; v.f = f;
    unsigned int u = v.u;
    return (unsigned short)((u + 0x7FFFu + ((u >> 16) & 1u)) >> 16);
}

// ---------------- cast fp32 -> bf16 (vectorized x4) ----------------
__global__ void cast_kernel(const float* __restrict__ in,
                            unsigned short* __restrict__ out, int n4) {
    int i = blockIdx.x * blockDim.x + threadIdx.x;
    if (i >= n4) return;
    floatx4 v = ((const floatx4*)in)[i];
    ushort4 o;
    o.x = f2bf(v.x); o.y = f2bf(v.y); o.z = f2bf(v.z); o.w = f2bf(v.w);
    ((ushort4*)out)[i] = o;
}

// ---------------- bf16 GEMM: Out = A @ W^T + bias ----------------
// A: M x K row-major bf16;  W: N x K row-major bf16 (torch Linear weight)
// mode 0: Out bf16 row-major MxN
// mode 1: Out bf16 written as V^T per head: [(b*NH+h)*NHD+hd][t]
// mode 2: Out fp32 row-major MxN
#define TM 128
#define TN 128
#define BK 32
#define LDP 40   // padded LDS leading dim (elems); 80B row stride, 16B aligned

__global__ __launch_bounds__(256) void gemm_bt(
    const unsigned short* __restrict__ A,
    const unsigned short* __restrict__ W,
    const float* __restrict__ bias,
    void* __restrict__ Out,
    int M, int N, int K, int mode)
{
    __shared__ __align__(16) unsigned short As[TM*LDP];
    __shared__ __align__(16) unsigned short Bs[TN*LDP];
    const int tid  = threadIdx.x;
    const int lane = tid & 63;
    const int wave = tid >> 6;
    const int quad = lane >> 4;
    const int l16  = lane & 15;
    const int wm = (wave >> 1) * 64;
    const int wn = (wave & 1) * 64;
    const int m_base = blockIdx.x * TM;
    const int n_base = blockIdx.y * TN;

    floatx4 acc[4][4];
    #pragma unroll
    for (int i = 0; i < 4; ++i)
        #pragma unroll
        for (int j = 0; j < 4; ++j)
            acc[i][j] = (floatx4){0.f, 0.f, 0.f, 0.f};

    const int sr = tid >> 2;          // staging row 0..63
    const int sc = (tid & 3) * 8;     // staging col group (8 bf16 = 16B)
    const int kTiles = K / BK;

    for (int kt = 0; kt < kTiles; ++kt) {
        const int k0 = kt * BK;
        __syncthreads();
        {
            uintx4 a0 = *(const uintx4*)&A[(size_t)(m_base + sr)      * K + k0 + sc];
            uintx4 a1 = *(const uintx4*)&A[(size_t)(m_base + sr + 64) * K + k0 + sc];
            uintx4 b0 = *(const uintx4*)&W[(size_t)(n_base + sr)      * K + k0 + sc];
            uintx4 b1 = *(const uintx4*)&W[(size_t)(n_base + sr + 64) * K + k0 + sc];
            *(uintx4*)&As[sr * LDP + sc]        = a0;
            *(uintx4*)&As[(sr + 64) * LDP + sc] = a1;
            *(uintx4*)&Bs[sr * LDP + sc]        = b0;
            *(uintx4*)&Bs[(sr + 64) * LDP + sc] = b1;
        }
        __syncthreads();

        bf16x8 af[4], bfr[4];
        #pragma unroll
        for (int mi = 0; mi < 4; ++mi)
            af[mi] = *(const bf16x8*)&As[(wm + mi*16 + l16) * LDP + quad*8];
        #pragma unroll
        for (int ni = 0; ni < 4; ++ni)
            bfr[ni] = *(const bf16x8*)&Bs[(wn + ni*16 + l16) * LDP + quad*8];

        #pragma unroll
        for (int mi = 0; mi < 4; ++mi)
            #pragma unroll
            for (int ni = 0; ni < 4; ++ni)
                acc[mi][ni] = __builtin_amdgcn_mfma_f32_16x16x32_bf16(
                    af[mi], bfr[ni], acc[mi][ni], 0, 0, 0);
    }

    // epilogue: C/D layout col = lane&15, row = quad*4 + reg
    #pragma unroll
    for (int mi = 0; mi < 4; ++mi) {
        #pragma unroll
        for (int ni = 0; ni < 4; ++ni) {
            const int col = n_base + wn + ni*16 + l16;
            const float bv = bias[col];
            #pragma unroll
            for (int r = 0; r < 4; ++r) {
                const int row = m_base + wm + mi*16 + quad*4 + r;
                const float v = acc[mi][ni][r] + bv;
                if (mode == 0) {
                    ((unsigned short*)Out)[(size_t)row * N + col] = f2bf(v);
                } else if (mode == 1) {
                    const int bb = row >> 11, t  = row & (NT - 1);
                    const int h  = col >> 6,  hd = col & (NHD - 1);
                    ((unsigned short*)Out)[(((size_t)(bb*NH + h))*NHD + hd)*NT + t] = f2bf(v);
                } else {
                    ((float*)Out)[(size_t)row * N + col] = v;
                }
            }
        }
    }
}

// ---------------- flash attention (causal), 1 wave per 16 Q-rows ----------------
#define SCALE 0.03125f                 // 1/sqrt(C) = 1/32
#define L2E   1.44269504088896340736f

__global__ __launch_bounds__(64) void flash_attn(
    const unsigned short* __restrict__ Q,    // (B,T,C) bf16
    const unsigned short* __restrict__ Kg,   // (B,T,C) bf16
    const unsigned short* __restrict__ Vt,   // (B,H,HD,T) bf16
    unsigned short* __restrict__ Y)          // (B,T,C) bf16
{
    __shared__ __align__(16) unsigned short Pl[16 * LDP];
    const int lane = threadIdx.x;
    const int quad = lane >> 4, l16 = lane & 15;
    const int q0 = blockIdx.x * 16;
    const int bh = blockIdx.y;
    const int b = bh >> 4, h = bh & (NH - 1);
    const unsigned short* Qp = Q  + (size_t)b * NT * NC + h * NHD;
    const unsigned short* Kp = Kg + (size_t)b * NT * NC + h * NHD;
    const unsigned short* Vp = Vt + (size_t)bh * NHD * NT;

    // Q A-fragments (rows q0..q0+15, d contiguous), loaded once
    bf16x8 qf[2];
    qf[0] = *(const bf16x8*)&Qp[(size_t)(q0 + l16) * NC + quad*8];
    qf[1] = *(const bf16x8*)&Qp[(size_t)(q0 + l16) * NC + 32 + quad*8];

    floatx4 o[4];
    #pragma unroll
    for (int nt = 0; nt < 4; ++nt) o[nt] = (floatx4){0.f, 0.f, 0.f, 0.f};
    float m_r[4], l_r[4];
    #pragma unroll
    for (int r = 0; r < 4; ++r) { m_r[r] = -__builtin_inff(); l_r[r] = 0.f; }

    const int jend = q0 + 16;   // causal: need j <= row, rows < q0+16
    for (int j0 = 0; j0 < jend; j0 += 32) {
        // K B-fragments: two 16-col tiles, d-steps 0..31 / 32..63
        bf16x8 kf0[2], kf1[2];
        kf0[0] = *(const bf16x8*)&Kp[(size_t)(j0      + l16) * NC +      quad*8];
        kf0[1] = *(const bf16x8*)&Kp[(size_t)(j0      + l16) * NC + 32 + quad*8];
        kf1[0] = *(const bf16x8*)&Kp[(size_t)(j0 + 16 + l16) * NC +      quad*8];
        kf1[1] = *(const bf16x8*)&Kp[(size_t)(j0 + 16 + l16) * NC + 32 + quad*8];

        floatx4 s0 = (floatx4){0.f,0.f,0.f,0.f};
        floatx4 s1 = (floatx4){0.f,0.f,0.f,0.f};
        s0 = __builtin_amdgcn_mfma_f32_16x16x32_bf16(qf[0], kf0[0], s0, 0,0,0);
        s0 = __builtin_amdgcn_mfma_f32_16x16x32_bf16(qf[1], kf0[1], s0, 0,0,0);
        s1 = __builtin_amdgcn_mfma_f32_16x16x32_bf16(qf[0], kf1[0], s1, 0,0,0);
        s1 = __builtin_amdgcn_mfma_f32_16x16x32_bf16(qf[1], kf1[1], s1, 0,0,0);

        float p0[4], p1[4], alpha[4];
        #pragma unroll
        for (int r = 0; r < 4; ++r) {
            const int row = q0 + quad*4 + r;
            float v0 = (j0      + l16 <= row) ? s0[r] * SCALE : -__builtin_inff();
            float v1 = (j0 + 16 + l16 <= row) ? s1[r] * SCALE : -__builtin_inff();
            float mx = fmaxf(v0, v1);
            #pragma unroll
            for (int off = 1; off < 16; off <<= 1)
                mx = fmaxf(mx, __shfl_xor(mx, off, 16));
            const float mnew = fmaxf(m_r[r], mx);
            alpha[r] = exp2f((m_r[r] - mnew) * L2E);
            m_r[r] = mnew;
            p0[r] = exp2f((v0 - mnew) * L2E);
            p1[r] = exp2f((v1 - mnew) * L2E);
            float ls = p0[r] + p1[r];
            #pragma unroll
            for (int off = 1; off < 16; off <<= 1)
                ls += __shfl_xor(ls, off, 16);
            l_r[r] = l_r[r] * alpha[r] + ls;
        }
        #pragma unroll
        for (int nt = 0; nt < 4; ++nt)
            #pragma unroll
            for (int r = 0; r < 4; ++r)
                o[nt][r] *= alpha[r];

        // P (C-layout) -> LDS -> A-layout fragments
        #pragma unroll
        for (int r = 0; r < 4; ++r) {
            Pl[(quad*4 + r) * LDP +      l16] = f2bf(p0[r]);
            Pl[(quad*4 + r) * LDP + 16 + l16] = f2bf(p1[r]);
        }
        __syncthreads();
        bf16x8 pf = *(const bf16x8*)&Pl[l16 * LDP + quad*8];

        // V B-fragments from V^T layout: row hd, k contiguous
        bf16x8 vf[4];
        #pragma unroll
        for (int nt = 0; nt < 4; ++nt)
            vf[nt] = *(const bf16x8*)&Vp[(size_t)(nt*16 + l16) * NT + j0 + quad*8];
        #pragma unroll
        for (int nt = 0; nt < 4; ++nt)
            o[nt] = __builtin_amdgcn_mfma_f32_16x16x32_bf16(pf, vf[nt], o[nt], 0,0,0);
        __syncthreads();
    }

    #pragma unroll
    for (int nt = 0; nt < 4; ++nt) {
        const int col = h * NHD + nt*16 + l16;
        #pragma unroll
        for (int r = 0; r < 4; ++r) {
            const int row = q0 + quad*4 + r;
            Y[((size_t)b * NT + row) * NC + col] = f2bf(o[nt][r] / l_r[r]);
        }
    }
}

// ---------------- launch ----------------
extern "C" void kernel_launch(void* const* d_in, const int* in_sizes, int n_in,
                              void* d_out, int out_size, void* d_ws, size_t ws_size,
                              hipStream_t stream) {
    const float* x  = (const float*)d_in[0];
    const float* Wq = (const float*)d_in[1];
    const float* bq = (const float*)d_in[2];
    const float* Wk = (const float*)d_in[3];
    const float* bk = (const float*)d_in[4];
    const float* Wv = (const float*)d_in[5];
    const float* bv = (const float*)d_in[6];
    const float* Wo = (const float*)d_in[7];
    const float* bo = (const float*)d_in[8];

    char* ws = (char*)d_ws;
    size_t off = 0;
    auto alloc = [&](size_t bytes) -> void* {
        void* p = ws + off;
        off += (bytes + 255) & ~(size_t)255;
        return p;
    };
    unsigned short* xb  = (unsigned short*)alloc((size_t)NM * NC * 2);
    unsigned short* Wqb = (unsigned short*)alloc((size_t)NC * NC * 2);
    unsigned short* Wkb = (unsigned short*)alloc((size_t)NC * NC * 2);
    unsigned short* Wvb = (unsigned short*)alloc((size_t)NC * NC * 2);
    unsigned short* Wob = (unsigned short*)alloc((size_t)NC * NC * 2);
    unsigned short* Qb  = (unsigned short*)alloc((size_t)NM * NC * 2);
    unsigned short* Kb  = (unsigned short*)alloc((size_t)NM * NC * 2);
    unsigned short* Vtb = (unsigned short*)alloc((size_t)NM * NC * 2);
    unsigned short* Yb  = (unsigned short*)alloc((size_t)NM * NC * 2);

    const int nx4 = NM * NC / 4;
    const int nw4 = NC * NC / 4;
    cast_kernel<<<(nx4 + 255)/256, 256, 0, stream>>>(x,  xb,  nx4);
    cast_kernel<<<(nw4 + 255)/256, 256, 0, stream>>>(Wq, Wqb, nw4);
    cast_kernel<<<(nw4 + 255)/256, 256, 0, stream>>>(Wk, Wkb, nw4);
    cast_kernel<<<(nw4 + 255)/256, 256, 0, stream>>>(Wv, Wvb, nw4);
    cast_kernel<<<(nw4 + 255)/256, 256, 0, stream>>>(Wo, Wob, nw4);

    dim3 gg(NM / TM, NC / TN);
    gemm_bt<<<gg, 256, 0, stream>>>(xb, Wqb, bq, Qb,  NM, NC, NC, 0);
    gemm_bt<<<gg, 256, 0, stream>>>(xb, Wkb, bk, Kb,  NM, NC, NC, 0);
    gemm_bt<<<gg, 256, 0, stream>>>(xb, Wvb, bv, Vtb, NM, NC, NC, 1);

    flash_attn<<<dim3(NT/16, NB*NH), 64, 0, stream>>>(Qb, Kb, Vtb, Yb);

    gemm_bt<<<gg, 256, 0, stream>>>(Yb, Wob, bo, d_out, NM, NC, NC, 2);
}